// Round 16
// baseline (44.211 us; speedup 1.0000x reference)
//
#include <hip/hip_runtime.h>

#define IMG_W 1024
#define IMG_H 1024

typedef float f32x4 __attribute__((ext_vector_type(4)));

// lgkm-only barrier (R12-validated): drains LDS ops, lets NT stores fly.
__device__ __forceinline__ void lgkm_barrier() {
    asm volatile("s_waitcnt lgkmcnt(0)" ::: "memory");
    __builtin_amdgcn_s_barrier();
    __builtin_amdgcn_sched_barrier(0);
}

// R12 structure (quad pipeline, 512 thr, 2 blocks/CU) + conflict-free packed
// histogram: hist[256][16] u32 words, two u16 counters per word. Thread t:
// column c2=(t>>1)&15, half t&1. Within a wave the atomic targets spread over
// bank-pair {c2,16+c2} with <=4 lanes each (2-way avg ~= free, m136), vs
// random 4-5-way for the plain per-wave scheme. Max count/counter = 512.
__global__ __launch_bounds__(512, 4) void clahe_kernel(const float* __restrict__ img,
                                                       float* __restrict__ out) {
    const int quad = blockIdx.x;          // 0..511
    const int t0 = quad << 2;             // first tile of the quad
    const int b  = t0 >> 6;
    const int ty = (t0 >> 3) & 7;
    const int tx = t0 & 7;                // 0 or 4

    const size_t base0 = ((size_t)b * IMG_H + (size_t)ty * 128) * IMG_W + (size_t)tx * 128;

    const int t = threadIdx.x;            // 0..511
    const int w = t >> 6;                 // wave id 0..7
    const int c2 = (t >> 1) & 15;         // packed-histogram column
    const unsigned int hinc = 1u << ((t & 1) << 4);

    __shared__ unsigned int hist[256 * 16];  // 16 KB packed
    __shared__ float cdf[2][256];            // 2 KB ping-pong
    __shared__ float exw[4];
    __shared__ float wsum[4];

    #pragma unroll
    for (int k = 0; k < 8; ++k) hist[t + (k << 9)] = 0u;
    lgkm_barrier();

    // thread's element j of a tile: row = (t>>5) + 16*j, col = (t&31)*4
    const size_t toff = (size_t)(t >> 5) * IMG_W + ((t & 31) << 2);
    const float* __restrict__ p0 = img + base0 + toff;
    float* __restrict__ d0 = out + base0 + toff;

    unsigned int pk[2][8];                // ping-pong packed 255-indices
    f32x4 v[8];

    auto binpack = [&](const f32x4 vv, unsigned int* pkp) {
        atomicAdd(&hist[(min(255, (int)(vv.x * 256.0f)) << 4) + c2], hinc);
        atomicAdd(&hist[(min(255, (int)(vv.y * 256.0f)) << 4) + c2], hinc);
        atomicAdd(&hist[(min(255, (int)(vv.z * 256.0f)) << 4) + c2], hinc);
        atomicAdd(&hist[(min(255, (int)(vv.w * 256.0f)) << 4) + c2], hinc);
        *pkp = (unsigned int)min(255, (int)(vv.x * 255.0f))
             | ((unsigned int)min(255, (int)(vv.y * 255.0f)) << 8)
             | ((unsigned int)min(255, (int)(vv.z * 255.0f)) << 16)
             | ((unsigned int)min(255, (int)(vv.w * 255.0f)) << 24);
    };

    // clip + scan -> cdf[s]; zeroes hist for the next tile.
    auto scan_fn = [&](int s) {
        int h = 0;
        float x = 0.0f;
        if (t < 256) {
            // bin t: sum 16 packed words, (t>>1)-rotated -> 2 lanes/bank (free)
            const int rowbase = t << 4;
            unsigned int acc = 0;
            #pragma unroll
            for (int j = 0; j < 16; ++j) {
                const unsigned int word = hist[rowbase + ((j + (t >> 1)) & 15)];
                acc += (word & 0xFFFFu) + (word >> 16);
            }
            h = (int)acc;

            float ex = (float)max(h - 128, 0);
            #pragma unroll
            for (int off = 32; off > 0; off >>= 1) ex += __shfl_xor(ex, off);
            if ((t & 63) == 0) exw[w] = ex;

            x = fminf((float)h, 128.0f);
            #pragma unroll
            for (int off = 1; off < 64; off <<= 1) {
                const float y = __shfl_up(x, off);
                if ((t & 63) >= off) x += y;
            }
            if ((t & 63) == 63) wsum[w] = x;
        }
        lgkm_barrier();
        // zero hist for next tile (reads completed above)
        #pragma unroll
        for (int k = 0; k < 8; ++k) hist[t + (k << 9)] = 0u;
        if (t < 256) {
            const float excess = exw[0] + exw[1] + exw[2] + exw[3];
            float prefix = 0.0f;
            if (w > 0) prefix += wsum[0];
            if (w > 1) prefix += wsum[1];
            if (w > 2) prefix += wsum[2];
            const float summinh = wsum[0] + wsum[1] + wsum[2] + wsum[3];
            const float e256 = excess * (1.0f / 256.0f);
            const float total = summinh + excess;
            cdf[s][t] = (x + prefix + (float)(t + 1) * e256) / total;
        }
    };

    #pragma unroll
    for (int i = 0; i < 4; ++i) {
        const float* pi = p0 + (size_t)i * 128;
        // issue this tile's 8 loads first (MLP), then overlap prev-tile store
        #pragma unroll
        for (int j = 0; j < 8; ++j)
            v[j] = *reinterpret_cast<const f32x4*>(pi + (size_t)j * 16 * IMG_W);

        if (i > 0) {
            float* dprev = d0 + (size_t)(i - 1) * 128;
            #pragma unroll
            for (int j = 0; j < 8; ++j) {
                const unsigned int u = pk[(i - 1) & 1][j];
                f32x4 o;
                o.x = cdf[(i - 1) & 1][u & 255u];
                o.y = cdf[(i - 1) & 1][(u >> 8) & 255u];
                o.z = cdf[(i - 1) & 1][(u >> 16) & 255u];
                o.w = cdf[(i - 1) & 1][u >> 24];
                __builtin_nontemporal_store(
                    o, reinterpret_cast<f32x4*>(dprev + (size_t)j * 16 * IMG_W));
            }
        }

        #pragma unroll
        for (int j = 0; j < 8; ++j) binpack(v[j], &pk[i & 1][j]);
        lgkm_barrier();

        scan_fn(i & 1);
        lgkm_barrier();
    }

    // epilogue: store tile 3
    {
        float* dprev = d0 + (size_t)3 * 128;
        #pragma unroll
        for (int j = 0; j < 8; ++j) {
            const unsigned int u = pk[1][j];
            f32x4 o;
            o.x = cdf[1][u & 255u];
            o.y = cdf[1][(u >> 8) & 255u];
            o.z = cdf[1][(u >> 16) & 255u];
            o.w = cdf[1][u >> 24];
            __builtin_nontemporal_store(
                o, reinterpret_cast<f32x4*>(dprev + (size_t)j * 16 * IMG_W));
        }
    }
}

extern "C" void kernel_launch(void* const* d_in, const int* in_sizes, int n_in,
                              void* d_out, int out_size, void* d_ws, size_t ws_size,
                              hipStream_t stream) {
    const float* img = (const float*)d_in[0];
    float* out = (float*)d_out;
    clahe_kernel<<<512, 512, 0, stream>>>(img, out);
}